// Round 10
// baseline (172.460 us; speedup 1.0000x reference)
//
#include <hip/hip_runtime.h>

// EuclidConv + BatchNorm (training stats), fp32 in/out.
// y = 2*conv(x,w) + t1 (+t2 cancels in BN).  bf16 MFMA implicit GEMM:
//   M=25088 pixels, N=256 chans, K=9 taps*128 ci.
// Round 10: round-9 verified compute path + BN fused via persistent blocks:
// grid=512 (exactly 2 blocks/CU -> all co-resident), blocks 0..271 own 2
// tiles; spin on a device-scope counter after stats, then normalize own
// tiles from L2-hot self-written y. bn_apply kernel removed.

typedef short  bf16x8 __attribute__((ext_vector_type(8)));
typedef float  f32x4  __attribute__((ext_vector_type(4)));

#define NPIX   784
#define CI_    128
#define CO_    256
#define NB_    32
#define M_     25088
#define SHIFT_ 1152.0f
#define BN_EPS 1e-5f
#define M_TOT  25088

// ws layout (bytes): xp [32][30][30][128] bf16 = 7,372,800 ; s [32][30][30] f32 ;
// stats [2][256] f32 ; wp [36][16][4][16][8] bf16 = 589,824 ; ctr u32
#define S_OFF   7372800
#define ST_OFF  7488000
#define WP_OFF  7490048
#define CTR_OFF 8079872
#define ZERO_F4 468128            // (ST_OFF + 2048) / 16 : zeroes xp + s + stats

#define SLAB_CHUNKS 4864          // 19*256; >= 10 rows * 30 * 16 = 4800
#define NTILES 784
#define NBLKS  512

__device__ __forceinline__ unsigned short f2bf(float f) {
    unsigned int u = __float_as_uint(f);
    unsigned int r = (u + 0x7FFFu + ((u >> 16) & 1u)) >> 16;
    return (unsigned short)r;
}

__device__ __forceinline__ void gload_lds16(const void* gsrc, void* ldst) {
    __builtin_amdgcn_global_load_lds(
        (const __attribute__((address_space(1))) void*)gsrc,
        (__attribute__((address_space(3))) void*)ldst, 16, 0, 0);
}

__global__ __launch_bounds__(256) void init_ws(float* ws) {
    int i = blockIdx.x * 256 + threadIdx.x;
    if (i < ZERO_F4) ((f32x4*)ws)[i] = (f32x4){0.f, 0.f, 0.f, 0.f};
    if (i == 0) *(unsigned int*)((char*)ws + CTR_OFF) = 0u;
}

// ---- pack x: NCHW f32 -> padded NHWC bf16, plus s = sum_ci x^2 (round-2) ----
__global__ __launch_bounds__(256) void pack_x(const float* __restrict__ x,
                                              unsigned short* __restrict__ xp,
                                              float* __restrict__ s) {
    const int n = blockIdx.x / 28, h = blockIdx.x % 28, tid = threadIdx.x;
    __shared__ float xs[128][29];
    __shared__ float part[8][28];

    #pragma unroll
    for (int i = 0; i < 14; ++i) {
        int e = tid + i * 256;
        int ci = e / 28, w = e - ci * 28;
        xs[ci][w] = x[(size_t)(n * 128 + ci) * 784 + h * 28 + w];
    }
    __syncthreads();
    #pragma unroll
    for (int i = 0; i < 14; ++i) {
        int e = tid + i * 256;
        int w = e >> 7, ci = e & 127;
        xp[((size_t)(n * 30 + h + 1) * 30 + (w + 1)) * 128 + ci] = f2bf(xs[ci][w]);
    }
    if (tid < 224) {
        int grp = tid / 28, w = tid - grp * 28;
        float a = 0.f;
        #pragma unroll
        for (int ci = grp * 16; ci < grp * 16 + 16; ++ci) a = fmaf(xs[ci][w], xs[ci][w], a);
        part[grp][w] = a;
    }
    __syncthreads();
    if (tid < 28) {
        float a = 0.f;
        #pragma unroll
        for (int g = 0; g < 8; ++g) a += part[g][tid];
        s[n * 900 + (h + 1) * 30 + (tid + 1)] = a;
    }
}

// ---- pack w (round-2 verified): wp[kblk(36)][ng(16)][kb(4)][cc(16)][k8(8)] ----
__global__ __launch_bounds__(256) void pack_w(const float* __restrict__ w,
                                              unsigned short* __restrict__ wp) {
    int o = blockIdx.x * 256 + threadIdx.x;      // < 294912
    int k8   = o & 7;
    int cc   = (o >> 3) & 15;
    int kb   = (o >> 7) & 3;
    int ng   = (o >> 9) & 15;
    int kblk = o >> 13;                          // 0..35
    int tap  = kblk >> 2;
    int ci   = (kblk & 3) * 32 + kb * 8 + k8;
    int co   = ng * 16 + cc;
    wp[o] = f2bf(w[(size_t)(co * 128 + ci) * 9 + tap]);
}

// ---- persistent MFMA implicit GEMM + fused BN ----
__global__ __launch_bounds__(256, 2) void econv(
        const unsigned short* __restrict__ xp, const unsigned short* __restrict__ wp,
        const float* __restrict__ s, float* __restrict__ y, float* __restrict__ stats,
        const float* __restrict__ gamma, const float* __restrict__ beta,
        unsigned int* __restrict__ ctr) {
    __shared__ unsigned short slab[SLAB_CHUNKS * 8];   // 77,824 B
    __shared__ float t1s[128];                         // t1 cache, later scale/bias

    const int tid = threadIdx.x;
    const int bid = blockIdx.x;
    const int myTiles = (bid < NTILES - NBLKS) ? 2 : 1;   // 272 dual, 240 single

    const int lane = tid & 63;
    const int wid  = tid >> 6;
    const int wm = wid >> 1, wn = wid & 1;
    const int l15 = lane & 15, l16 = lane >> 4;

    #pragma unroll 1
    for (int tt = 0; tt < myTiles; ++tt) {
        const int tile = (tt == 0) ? bid : (NBLKS + bid);
        // XCD-aware bijective swizzle (784 = 8*98)
        int swz = (tile & 7) * 98 + (tile >> 3);
        const int nb = swz & 3;
        const int mb = swz >> 2;
        const int gblock = mb * 128;
        const int nblock = nb * 64;
        const int ng0 = nb * 4;

        const int n0  = gblock / 784;
        const int p0  = gblock - n0 * 784;
        const int GR0 = n0 * 30 + p0 / 28;
        const unsigned short* slabg = xp + (size_t)GR0 * 30 * 128;

        // stage slab once: linear LDS dest, source pre-swizzled.
        #pragma unroll
        for (int i = 0; i < 19; ++i) {
            int sc = tid + i * 256;
            int Q = sc >> 4, sl = sc & 15;
            int c = (sl & 8) | ((sl & 7) ^ (Q & 7));
            gload_lds16(slabg + (size_t)(Q * 16 + c) * 8, &slab[sc * 8]);
        }

        // t1 = 3x3 box of padded per-pixel sum of x^2
        if (tid < 128) {
            int g = gblock + tid; int n = g / 784, p = g - n * 784;
            int h = p / 28, wq = p - h * 28;
            const float* sb = s + n * 900 + h * 30 + wq;
            t1s[tid] = (sb[0] + sb[1] + sb[2]) + (sb[30] + sb[31] + sb[32]) + (sb[60] + sb[61] + sb[62]);
        }

        int Pp[4];
        #pragma unroll
        for (int fm = 0; fm < 4; ++fm) {
            int g = gblock + wm * 64 + fm * 16 + l15;
            int n = g / 784, p = g - n * 784;
            int h = p / 28, c = p - h * 28;
            Pp[fm] = (n * 30 + h - GR0) * 30 + c;
        }
        const unsigned short* wpl = wp + (size_t)((ng0 + wn * 2) * 64 + l16 * 16 + l15) * 8;

        f32x4 acc[4][2];
        #pragma unroll
        for (int a_ = 0; a_ < 4; ++a_)
            #pragma unroll
            for (int b_ = 0; b_ < 2; ++b_) acc[a_][b_] = (f32x4){0.f, 0.f, 0.f, 0.f};

        __syncthreads();   // slab + t1s ready; no barriers in K-loop

#define LOADK(ks, A, B) {                                                    \
    const int tap_ = (ks) >> 1, half_ = (ks) & 1;                            \
    const int toff_ = (tap_ / 3) * 30 + (tap_ % 3);                          \
    _Pragma("unroll") for (int q_ = 0; q_ < 2; ++q_) {                       \
        _Pragma("unroll") for (int fm_ = 0; fm_ < 4; ++fm_) {                \
            int P2_ = Pp[fm_] + toff_;                                       \
            int sl_ = half_ * 8 + ((q_ * 4 + l16) ^ (P2_ & 7));              \
            A[q_][fm_] = *(const bf16x8*)&slab[(P2_ * 16 + sl_) * 8];        \
        }                                                                    \
        const int K16_ = (tap_ * 4 + half_ * 2 + q_) * 16;                   \
        _Pragma("unroll") for (int fn_ = 0; fn_ < 2; ++fn_)                  \
            B[q_][fn_] = *(const bf16x8*)&wpl[(size_t)(K16_ + fn_) * 512];   \
    }                                                                        \
}
        bf16x8 aP[2][2][4], bP[2][2][2];
        LOADK(0, aP[0], bP[0]);
        #pragma unroll
        for (int ks = 0; ks < 18; ++ks) {
            const int cur = ks & 1;
            if (ks < 17) LOADK(ks + 1, aP[cur ^ 1], bP[cur ^ 1]);
            #pragma unroll
            for (int q = 0; q < 2; ++q)
                #pragma unroll
                for (int fm = 0; fm < 4; ++fm)
                    #pragma unroll
                    for (int fn = 0; fn < 2; ++fn)
                        acc[fm][fn] = __builtin_amdgcn_mfma_f32_16x16x32_bf16(
                            aP[cur][q][fm], bP[cur][q][fn], acc[fm][fn], 0, 0, 0);
        }
#undef LOADK

        // epilogue: coalesced pre-BN store via LDS transpose (slab reused)
        __syncthreads();
        float* ldsT = (float*)slab;   // [64 co][132] floats

        float sSum[2] = {0.f, 0.f}, sSq[2] = {0.f, 0.f};
        #pragma unroll
        for (int fm = 0; fm < 4; ++fm) {
            #pragma unroll
            for (int j = 0; j < 4; ++j) {
                int r = wm * 64 + fm * 16 + l16 * 4 + j;
                float t1v = t1s[r];
                #pragma unroll
                for (int fn = 0; fn < 2; ++fn) {
                    float v = fmaf(2.f, acc[fm][fn][j], t1v);
                    ldsT[(wn * 32 + fn * 16 + l15) * 132 + r] = v;
                    float d = v - SHIFT_;
                    sSum[fn] += d;
                    sSq[fn] = fmaf(d, d, sSq[fn]);
                }
            }
        }
        __syncthreads();
        #pragma unroll
        for (int i = 0; i < 8; ++i) {
            int idx = tid + i * 256;
            int co  = idx >> 5;
            int r   = (idx & 31) * 4;
            int g   = gblock + r;
            int n = g / 784, p = g - n * 784;
            f32x4 v = *(const f32x4*)&ldsT[co * 132 + r];
            *(f32x4*)&y[(size_t)n * 200704 + (size_t)(nblock + co) * 784 + p] = v;
        }

        #pragma unroll
        for (int fn = 0; fn < 2; ++fn) {
            float a = sSum[fn], b2 = sSq[fn];
            a  += __shfl_xor(a, 16);  a  += __shfl_xor(a, 32);
            b2 += __shfl_xor(b2, 16); b2 += __shfl_xor(b2, 32);
            if (l16 == 0) {
                int co = nblock + wn * 32 + fn * 16 + l15;
                atomicAdd(&stats[co], a);
                atomicAdd(&stats[256 + co], b2);
            }
        }
        __syncthreads();   // protect slab/ldsT before next tile's staging
    }

    // ---- grid-wide arrival + spin (all 512 blocks co-resident: 2/CU) ----
    if (tid == 0) {
        __hip_atomic_fetch_add(ctr, 1u, __ATOMIC_ACQ_REL, __HIP_MEMORY_SCOPE_AGENT);
        while (__hip_atomic_load(ctr, __ATOMIC_ACQUIRE, __HIP_MEMORY_SCOPE_AGENT) < NBLKS)
            __builtin_amdgcn_s_sleep(8);
    }
    __syncthreads();

    // ---- normalize own tiles (self-written y: same-CU L2, coherent) ----
    const float invM = 1.0f / (float)M_TOT;
    #pragma unroll 1
    for (int tt = 0; tt < myTiles; ++tt) {
        const int tile = (tt == 0) ? bid : (NBLKS + bid);
        int swz = (tile & 7) * 98 + (tile >> 3);
        const int nb = swz & 3;
        const int mb = swz >> 2;
        const int gblock = mb * 128;
        const int nblock = nb * 64;

        if (tid < 64) {
            int c = nblock + tid;
            float su = __hip_atomic_load(&stats[c], __ATOMIC_RELAXED, __HIP_MEMORY_SCOPE_AGENT);
            float s2 = __hip_atomic_load(&stats[256 + c], __ATOMIC_RELAXED, __HIP_MEMORY_SCOPE_AGENT);
            float ms   = su * invM;
            float var  = fmaf(-ms, ms, s2 * invM);
            float mean = SHIFT_ + ms;
            float scale = rsqrtf(var + BN_EPS) * gamma[c];
            float bias  = beta[c] - mean * scale;
            t1s[tid] = scale;
            t1s[64 + tid] = bias;
        }
        __syncthreads();
        #pragma unroll
        for (int i = 0; i < 8; ++i) {
            int idx = tid + i * 256;
            int co  = idx >> 5;
            int r   = (idx & 31) * 4;
            int g   = gblock + r;
            int n = g / 784, p = g - n * 784;
            float* yp = &y[(size_t)n * 200704 + (size_t)(nblock + co) * 784 + p];
            float sc = t1s[co], bi = t1s[64 + co];
            f32x4 v = *(const f32x4*)yp;
            v.x = fmaf(v.x, sc, bi);
            v.y = fmaf(v.y, sc, bi);
            v.z = fmaf(v.z, sc, bi);
            v.w = fmaf(v.w, sc, bi);
            *(f32x4*)yp = v;
        }
        __syncthreads();
    }
}

extern "C" void kernel_launch(void* const* d_in, const int* in_sizes, int n_in,
                              void* d_out, int out_size, void* d_ws, size_t ws_size,
                              hipStream_t stream) {
    const float* x     = (const float*)d_in[0];
    const float* w     = (const float*)d_in[1];
    const float* gamma = (const float*)d_in[2];
    const float* beta  = (const float*)d_in[3];
    float* y = (float*)d_out;

    char* ws = (char*)d_ws;
    unsigned short* xp    = (unsigned short*)(ws);
    float*          s     = (float*)(ws + S_OFF);
    float*          stats = (float*)(ws + ST_OFF);
    unsigned short* wp    = (unsigned short*)(ws + WP_OFF);
    unsigned int*   ctr   = (unsigned int*)(ws + CTR_OFF);

    init_ws<<<(ZERO_F4 + 255) / 256, 256, 0, stream>>>((float*)ws);
    pack_x<<<NB_ * 28, 256, 0, stream>>>(x, xp, s);
    pack_w<<<1152, 256, 0, stream>>>(w, wp);
    econv<<<NBLKS, 256, 0, stream>>>(xp, wp, s, y, stats, gamma, beta, ctr);
}

// Round 11
// 57.658 us; speedup vs baseline: 2.9911x; 2.9911x over previous
//
#include <hip/hip_runtime.h>

// EuclidConv + BatchNorm (training stats), fp32 in/out.
// y = 2*conv(x,w) + t1 (+t2 cancels in BN).  bf16 MFMA implicit GEMM:
//   M=25088 pixels, N=256 chans, K=9 taps*128 ci.
// Round 11: revert r10 persistence (scratch-spill + imbalance regression).
// r9 base with BN=128: 392 tiles -> ALL co-resident in one round (2/CU),
// halved slab+wp traffic. No explicit reg prefetch (r9 delta was -1.3us).

typedef short  bf16x8 __attribute__((ext_vector_type(8)));
typedef float  f32x4  __attribute__((ext_vector_type(4)));

#define NPIX   784
#define CI_    128
#define CO_    256
#define NB_    32
#define M_     25088
#define SHIFT_ 1152.0f
#define BN_EPS 1e-5f
#define M_TOT  25088

// ws layout (bytes): xp [32][30][30][128] bf16 = 7,372,800 ; s [32][30][30] f32 ;
// stats [2][256] f32 ; wp [36][16][4][16][8] bf16 = 589,824 (round-2 layout)
#define S_OFF   7372800
#define ST_OFF  7488000
#define WP_OFF  7490048
#define ZERO_F4 468128            // (ST_OFF + 2048) / 16 : zeroes xp + s + stats

#define SLAB_CHUNKS 4864          // 19*256; >= 10 rows * 30 * 16 = 4800

__device__ __forceinline__ unsigned short f2bf(float f) {
    unsigned int u = __float_as_uint(f);
    unsigned int r = (u + 0x7FFFu + ((u >> 16) & 1u)) >> 16;
    return (unsigned short)r;
}

__device__ __forceinline__ void gload_lds16(const void* gsrc, void* ldst) {
    __builtin_amdgcn_global_load_lds(
        (const __attribute__((address_space(1))) void*)gsrc,
        (__attribute__((address_space(3))) void*)ldst, 16, 0, 0);
}

__global__ __launch_bounds__(256) void init_ws(float* ws) {
    int i = blockIdx.x * 256 + threadIdx.x;
    if (i < ZERO_F4) ((f32x4*)ws)[i] = (f32x4){0.f, 0.f, 0.f, 0.f};
}

// ---- pack x: NCHW f32 -> padded NHWC bf16, plus s = sum_ci x^2 (round-2) ----
__global__ __launch_bounds__(256) void pack_x(const float* __restrict__ x,
                                              unsigned short* __restrict__ xp,
                                              float* __restrict__ s) {
    const int n = blockIdx.x / 28, h = blockIdx.x % 28, tid = threadIdx.x;
    __shared__ float xs[128][29];
    __shared__ float part[8][28];

    #pragma unroll
    for (int i = 0; i < 14; ++i) {
        int e = tid + i * 256;
        int ci = e / 28, w = e - ci * 28;
        xs[ci][w] = x[(size_t)(n * 128 + ci) * 784 + h * 28 + w];
    }
    __syncthreads();
    #pragma unroll
    for (int i = 0; i < 14; ++i) {
        int e = tid + i * 256;
        int w = e >> 7, ci = e & 127;
        xp[((size_t)(n * 30 + h + 1) * 30 + (w + 1)) * 128 + ci] = f2bf(xs[ci][w]);
    }
    if (tid < 224) {
        int grp = tid / 28, w = tid - grp * 28;
        float a = 0.f;
        #pragma unroll
        for (int ci = grp * 16; ci < grp * 16 + 16; ++ci) a = fmaf(xs[ci][w], xs[ci][w], a);
        part[grp][w] = a;
    }
    __syncthreads();
    if (tid < 28) {
        float a = 0.f;
        #pragma unroll
        for (int g = 0; g < 8; ++g) a += part[g][tid];
        s[n * 900 + (h + 1) * 30 + (tid + 1)] = a;
    }
}

// ---- pack w (round-2 verified): wp[kblk(36)][ng(16)][kb(4)][cc(16)][k8(8)] ----
__global__ __launch_bounds__(256) void pack_w(const float* __restrict__ w,
                                              unsigned short* __restrict__ wp) {
    int o = blockIdx.x * 256 + threadIdx.x;      // < 294912
    int k8   = o & 7;
    int cc   = (o >> 3) & 15;
    int kb   = (o >> 7) & 3;
    int ng   = (o >> 9) & 15;
    int kblk = o >> 13;                          // 0..35
    int tap  = kblk >> 2;
    int ci   = (kblk & 3) * 32 + kb * 8 + k8;
    int co   = ng * 16 + cc;
    wp[o] = f2bf(w[(size_t)(co * 128 + ci) * 9 + tap]);
}

// ---- MFMA implicit GEMM: BM=128, BN=128, 4 waves (2x2 of 64x64) ----
// A-slab resident in LDS (staged once, 10 rows); barrier-free K-loop;
// coalesced LDS-transpose epilogue. 392 blocks, all co-resident (2/CU).
__global__ __launch_bounds__(256, 2) void econv(
        const unsigned short* __restrict__ xp, const unsigned short* __restrict__ wp,
        const float* __restrict__ s, float* __restrict__ y, float* __restrict__ stats) {
    __shared__ unsigned short slab[SLAB_CHUNKS * 8];   // 77,824 B: 10 padded rows
    __shared__ float t1s[128];

    const int tid = threadIdx.x;
    // XCD-aware bijective swizzle (392 = 8*49)
    int bid = blockIdx.x;
    int swz = (bid & 7) * 49 + (bid >> 3);
    const int nb = swz & 1;
    const int mb = swz >> 1;
    const int gblock = mb * 128;
    const int nblock = nb * 128;
    const int ng0 = nb * 8;

    // slab covers global padded rows GR0..GR0+9 (crossing blocks need 10)
    const int n0  = gblock / 784;
    const int p0  = gblock - n0 * 784;
    const int GR0 = n0 * 30 + p0 / 28;
    const unsigned short* slabg = xp + (size_t)GR0 * 30 * 128;

    // stage slab once: linear LDS dest, source pre-swizzled.
    // slot sl of pixel Q holds source chunk c = (sl&8)|((sl&7)^(Q&7)).
    #pragma unroll
    for (int i = 0; i < 19; ++i) {
        int sc = tid + i * 256;
        int Q = sc >> 4, sl = sc & 15;
        int c = (sl & 8) | ((sl & 7) ^ (Q & 7));
        gload_lds16(slabg + (size_t)(Q * 16 + c) * 8, &slab[sc * 8]);
    }

    // t1 = 3x3 box of padded per-pixel sum of x^2
    if (tid < 128) {
        int g = gblock + tid; int n = g / 784, p = g - n * 784;
        int h = p / 28, wq = p - h * 28;
        const float* sb = s + n * 900 + h * 30 + wq;
        t1s[tid] = (sb[0] + sb[1] + sb[2]) + (sb[30] + sb[31] + sb[32]) + (sb[60] + sb[61] + sb[62]);
    }

    const int lane = tid & 63;
    const int wid  = tid >> 6;
    const int wm = wid >> 1, wn = wid & 1;
    const int l15 = lane & 15, l16 = lane >> 4;

    // per-lane slab pixel index (3x3 window top-left) for each fm row
    int Pp[4];
    #pragma unroll
    for (int fm = 0; fm < 4; ++fm) {
        int g = gblock + wm * 64 + fm * 16 + l15;
        int n = g / 784, p = g - n * 784;
        int h = p / 28, c = p - h * 28;
        Pp[fm] = (n * 30 + h - GR0) * 30 + c;
    }
    // per-lane B base: wave wn covers ngs ng0+wn*4 .. +3 (64 channels)
    const unsigned short* wpl = wp + (size_t)((ng0 + wn * 4) * 64 + l16 * 16 + l15) * 8;

    f32x4 acc[4][4];
    #pragma unroll
    for (int a_ = 0; a_ < 4; ++a_)
        #pragma unroll
        for (int b_ = 0; b_ < 4; ++b_) acc[a_][b_] = (f32x4){0.f, 0.f, 0.f, 0.f};

    __syncthreads();   // slab + t1s ready; no barriers in K-loop

    #pragma unroll
    for (int tap = 0; tap < 9; ++tap) {
        const int toff = (tap / 3) * 30 + (tap % 3);
        #pragma unroll
        for (int half = 0; half < 2; ++half) {
            bf16x8 aF[2][4], bF[2][4];
            #pragma unroll
            for (int q = 0; q < 2; ++q) {
                #pragma unroll
                for (int fm = 0; fm < 4; ++fm) {
                    int P2 = Pp[fm] + toff;
                    int sl = half * 8 + ((q * 4 + l16) ^ (P2 & 7));
                    aF[q][fm] = *(const bf16x8*)&slab[(P2 * 16 + sl) * 8];
                }
                const int K16 = (tap * 4 + half * 2 + q) * 16;
                #pragma unroll
                for (int fn = 0; fn < 4; ++fn)
                    bF[q][fn] = *(const bf16x8*)&wpl[(size_t)(K16 + fn) * 512];
            }
            #pragma unroll
            for (int q = 0; q < 2; ++q)
                #pragma unroll
                for (int fm = 0; fm < 4; ++fm)
                    #pragma unroll
                    for (int fn = 0; fn < 4; ++fn)
                        acc[fm][fn] = __builtin_amdgcn_mfma_f32_16x16x32_bf16(
                            aF[q][fm], bF[q][fn], acc[fm][fn], 0, 0, 0);
        }
    }

    // ---- epilogue: coalesced via LDS transpose (slab reused) ----
    __syncthreads();   // all waves finished reading slab
    float* ldsT = (float*)slab;   // [128 co][132] floats = 67,584 B

    float sSum[4] = {0.f, 0.f, 0.f, 0.f}, sSq[4] = {0.f, 0.f, 0.f, 0.f};
    #pragma unroll
    for (int fm = 0; fm < 4; ++fm) {
        #pragma unroll
        for (int j = 0; j < 4; ++j) {
            int r = wm * 64 + fm * 16 + l16 * 4 + j;
            float t1v = t1s[r];
            #pragma unroll
            for (int fn = 0; fn < 4; ++fn) {
                float v = fmaf(2.f, acc[fm][fn][j], t1v);
                ldsT[(wn * 64 + fn * 16 + l15) * 132 + r] = v;
                float d = v - SHIFT_;
                sSum[fn] += d;
                sSq[fn] = fmaf(d, d, sSq[fn]);
            }
        }
    }
    __syncthreads();
    // coalesced store: thread reads f32x4 per (co, 4 consecutive pixels)
    #pragma unroll
    for (int i = 0; i < 16; ++i) {
        int idx = tid + i * 256;       // 0..4095
        int co  = idx >> 5;            // 0..127
        int r   = (idx & 31) * 4;      // block-local pixel, mult of 4
        int g   = gblock + r;
        int n = g / 784, p = g - n * 784;   // crossings at mult of 16: never split
        f32x4 v = *(const f32x4*)&ldsT[co * 132 + r];
        *(f32x4*)&y[(size_t)n * 200704 + (size_t)(nblock + co) * 784 + p] = v;
    }

    #pragma unroll
    for (int fn = 0; fn < 4; ++fn) {
        float a = sSum[fn], b2 = sSq[fn];
        a  += __shfl_xor(a, 16);  a  += __shfl_xor(a, 32);
        b2 += __shfl_xor(b2, 16); b2 += __shfl_xor(b2, 32);
        if (l16 == 0) {
            int co = nblock + wn * 64 + fn * 16 + l15;
            atomicAdd(&stats[co], a);
            atomicAdd(&stats[256 + co], b2);
        }
    }
}

__global__ __launch_bounds__(256) void bn_apply(
        float* __restrict__ y, const float* __restrict__ stats,
        const float* __restrict__ gamma, const float* __restrict__ beta) {
    const int TOTAL4 = NB_ * CO_ * NPIX / 4;
    int i4 = blockIdx.x * 256 + threadIdx.x;
    if (i4 >= TOTAL4) return;
    int c = (i4 / (NPIX / 4)) & (CO_ - 1);
    float su = stats[c];
    float s2 = stats[CO_ + c];
    const float invM = 1.0f / (float)M_TOT;
    float ms   = su * invM;
    float var  = fmaf(-ms, ms, s2 * invM);
    float mean = SHIFT_ + ms;
    float scale = rsqrtf(var + BN_EPS) * gamma[c];
    float bias  = beta[c] - mean * scale;
    f32x4 v = ((const f32x4*)y)[i4];
    v.x = fmaf(v.x, scale, bias);
    v.y = fmaf(v.y, scale, bias);
    v.z = fmaf(v.z, scale, bias);
    v.w = fmaf(v.w, scale, bias);
    ((f32x4*)y)[i4] = v;
}

extern "C" void kernel_launch(void* const* d_in, const int* in_sizes, int n_in,
                              void* d_out, int out_size, void* d_ws, size_t ws_size,
                              hipStream_t stream) {
    const float* x     = (const float*)d_in[0];
    const float* w     = (const float*)d_in[1];
    const float* gamma = (const float*)d_in[2];
    const float* beta  = (const float*)d_in[3];
    float* y = (float*)d_out;

    char* ws = (char*)d_ws;
    unsigned short* xp    = (unsigned short*)(ws);
    float*          s     = (float*)(ws + S_OFF);
    float*          stats = (float*)(ws + ST_OFF);
    unsigned short* wp    = (unsigned short*)(ws + WP_OFF);

    init_ws<<<(ZERO_F4 + 255) / 256, 256, 0, stream>>>((float*)ws);
    pack_x<<<NB_ * 28, 256, 0, stream>>>(x, xp, s);
    pack_w<<<1152, 256, 0, stream>>>(w, wp);
    econv<<<392, 256, 0, stream>>>(xp, wp, s, y, stats);
    bn_apply<<<(NB_ * CO_ * NPIX / 4 + 255) / 256, 256, 0, stream>>>(y, stats, gamma, beta);
}